// Round 10
// baseline (314.589 us; speedup 1.0000x reference)
//
#include <hip/hip_runtime.h>
#include <hip/hip_bf16.h>
#include <stdint.h>

typedef __bf16 bf16x8 __attribute__((ext_vector_type(8)));
typedef float f32x4 __attribute__((ext_vector_type(4)));

constexpr int S = 1024, Bsz = 16, Hd = 1024;
constexpr int M = S * Bsz;   // 16384
constexpr int N = 3 * Hd;    // 3072
constexpr int K = 1024;
constexpr int BM = 128, BN = 128, BK = 32;   // BK=32 (R2/R9-proven)
constexpr int NCH = 64, CS = S / NCH;  // 64 chunks x 16 steps
constexpr int BH = Bsz * Hd;           // 16384
constexpr int EP = 136;                // epilogue LDS row stride (272B, 16B-aligned)

__device__ __forceinline__ float fast_sigmoid(float x) { return 1.0f / (1.0f + __expf(-x)); }
__device__ __forceinline__ float fast_tanh(float x) { return 2.0f / (1.0f + __expf(-2.0f * x)) - 1.0f; }

// async global->LDS 16B per lane; LDS dest is wave-uniform base + lane*16
__device__ __forceinline__ void gld_lds16(const __bf16* g, __bf16* l) {
  __builtin_amdgcn_global_load_lds(
      (const __attribute__((address_space(1))) void*)g,
      (__attribute__((address_space(3))) void*)l,
      16, 0, 0);
}

// ---- fp32 -> bf16 conversion for BOTH X and W in one launch ----
__global__ void convert_all(const float* __restrict__ X, const float* __restrict__ W,
                            __bf16* __restrict__ Xb, __bf16* __restrict__ Wb) {
  int i = blockIdx.x * blockDim.x + threadIdx.x;  // 0 .. 2490367
  const float* src; __bf16* dst; int idx;
  if (i < 2097152) { src = X; dst = Xb; idx = i; }
  else             { src = W; dst = Wb; idx = i - 2097152; }
  const float4* s4 = (const float4*)src;
  float4 a = s4[2 * idx], b = s4[2 * idx + 1];
  bf16x8 v;
  v[0] = (__bf16)a.x; v[1] = (__bf16)a.y; v[2] = (__bf16)a.z; v[3] = (__bf16)a.w;
  v[4] = (__bf16)b.x; v[5] = (__bf16)b.y; v[6] = (__bf16)b.z; v[7] = (__bf16)b.w;
  *((bf16x8*)dst + idx) = v;
}

// ---- bf16 MFMA GEMM (NT: C[m,n] = sum_k A[m,k]*W[n,k]) + bias + activation ----
// 2-PHASE double-buffered K-loop (guide T3 minimum recipe): issue next-tile
// global_load_lds BEFORE computing current tile; ONE barrier per K-step
// (its implicit vmcnt(0)+lgkmcnt(0) drain orders everything).
// Race-freedom: STAGE writes nxt, which no wave touches (tile t-1 reads
// drained at previous barrier); ds_reads hit cur only.
// R3-proven full-tile LDS epilogue (coalesced 256B stores) unchanged.
__global__ __launch_bounds__(256) void gemm_act(const __bf16* __restrict__ A,
                                                const __bf16* __restrict__ Bw,
                                                const float* __restrict__ bias,
                                                __bf16* __restrict__ Y) {
  // staging: 2 x (As 4096 + Bs 4096) elems = 32KB, overlaid on the
  // epilogue tile [128][EP] bf16 = 34816B (LDS_Block unchanged vs R9).
  __shared__ __align__(16) __bf16 smem[BM * EP];  // 34816 B
  __bf16* As0 = smem;             // buf0 A: 4096 elems
  __bf16* Bs0 = smem + 4096;      // buf0 B
  __bf16* As1 = smem + 8192;      // buf1 A
  __bf16* Bs1 = smem + 12288;     // buf1 B
  const int t = threadIdx.x;
  const int lane = t & 63;
  const int wave = t >> 6;
  const int wm = wave >> 1, wn = wave & 1;
  const int tn = blockIdx.x % (N / BN);   // natural order (XCD swizzle hurt FETCH, R3)
  const int tm = blockIdx.x / (N / BN);
  const int m0 = tm * BM, n0 = tn * BN;
  const int lrow = lane & 15;
  const int quad = lane >> 4;

  // per-lane global staging addresses
  const int srow = t >> 2;      // 0..63
  const int scw = t & 3;        // 16B sub-chunk within 32-elem row
  const __bf16* gA0 = A + (size_t)(m0 + srow) * K + scw * 8;
  const __bf16* gA1 = gA0 + (size_t)64 * K;
  const __bf16* gB0 = Bw + (size_t)(n0 + srow) * K + scw * 8;
  const __bf16* gB1 = gB0 + (size_t)64 * K;
  const int wofs = wave * 512;  // wave-uniform LDS offset within a buffer

  f32x4 acc[4][4] = {};

  // ---- prologue: stage tile 0 into buf0 ----
  gld_lds16(gA0, As0 + wofs);
  gld_lds16(gA1, As0 + 2048 + wofs);
  gld_lds16(gB0, Bs0 + wofs);
  gld_lds16(gB1, Bs0 + 2048 + wofs);
  gA0 += BK; gA1 += BK; gB0 += BK; gB1 += BK;
  __syncthreads();  // implicit vmcnt(0): tile 0 resident

  __bf16* curA = As0; __bf16* curB = Bs0;
  __bf16* nxtA = As1; __bf16* nxtB = Bs1;

  for (int kt = 0; kt < K / BK - 1; ++kt) {
    // 1) issue next-tile stage (overlaps with this tile's ds_read+MFMA)
    gld_lds16(gA0, nxtA + wofs);
    gld_lds16(gA1, nxtA + 2048 + wofs);
    gld_lds16(gB0, nxtB + wofs);
    gld_lds16(gB1, nxtB + 2048 + wofs);
    gA0 += BK; gA1 += BK; gB0 += BK; gB1 += BK;

    // 2) compute current tile
    bf16x8 af[4], bfr[4];
#pragma unroll
    for (int mi = 0; mi < 4; ++mi)
      af[mi] = *(const bf16x8*)(&curA[(wm * 64 + mi * 16 + lrow) * BK + quad * 8]);
#pragma unroll
    for (int ni = 0; ni < 4; ++ni)
      bfr[ni] = *(const bf16x8*)(&curB[(wn * 64 + ni * 16 + lrow) * BK + quad * 8]);
#pragma unroll
    for (int mi = 0; mi < 4; ++mi)
#pragma unroll
      for (int ni = 0; ni < 4; ++ni)
        acc[mi][ni] = __builtin_amdgcn_mfma_f32_16x16x32_bf16(af[mi], bfr[ni], acc[mi][ni], 0, 0, 0);

    // 3) single barrier: drains vmcnt (next tile resident) + lgkm
    __syncthreads();
    __bf16* tA = curA; curA = nxtA; nxtA = tA;
    __bf16* tB = curB; curB = nxtB; nxtB = tB;
  }

  // ---- final tile: compute only, no prefetch ----
  {
    bf16x8 af[4], bfr[4];
#pragma unroll
    for (int mi = 0; mi < 4; ++mi)
      af[mi] = *(const bf16x8*)(&curA[(wm * 64 + mi * 16 + lrow) * BK + quad * 8]);
#pragma unroll
    for (int ni = 0; ni < 4; ++ni)
      bfr[ni] = *(const bf16x8*)(&curB[(wn * 64 + ni * 16 + lrow) * BK + quad * 8]);
#pragma unroll
    for (int mi = 0; mi < 4; ++mi)
#pragma unroll
      for (int ni = 0; ni < 4; ++ni)
        acc[mi][ni] = __builtin_amdgcn_mfma_f32_16x16x32_bf16(af[mi], bfr[ni], acc[mi][ni], 0, 0, 0);
  }

  // ---- epilogue (R3/R9-proven): activation -> LDS [128][EP] -> coalesced global ----
  __syncthreads();  // all ds_reads done; reuse smem as epilogue tile
#pragma unroll
  for (int ni = 0; ni < 4; ++ni) {
    int colL = wn * 64 + ni * 16 + lrow;
    int col = n0 + colL;
    float bv = bias[col];
    bool is_tanh = (col < Hd);
#pragma unroll
    for (int mi = 0; mi < 4; ++mi) {
#pragma unroll
      for (int r = 0; r < 4; ++r) {
        int rowL = wm * 64 + mi * 16 + quad * 4 + r;  // C/D: col=lane&15, row=quad*4+r
        float y = acc[mi][ni][r] + bv;
        float v = is_tanh ? fast_tanh(y) : fast_sigmoid(y);
        smem[rowL * EP + colL] = (__bf16)v;
      }
    }
  }
  __syncthreads();
  // 128 rows x 128 cols bf16: each thread stores one bf16x8; 16 threads cover a 256B row
#pragma unroll
  for (int it = 0; it < 8; ++it) {
    int slot = it * 256 + t;
    int rowL = slot >> 4;
    int cw = slot & 15;
    bf16x8 vv = *(const bf16x8*)(&smem[rowL * EP + cw * 8]);
    *(bf16x8*)(&Y[(size_t)(m0 + rowL) * N + n0 + cw * 8]) = vv;
  }
}

// ---- chunked affine scan: h_t = f*z + (1-f)*h == a*h + b, a=1-f, b=f*z ----
// pass1: per-chunk composition (A,B): h_out = A*h_in + B  (R3/R9-proven)
__global__ __launch_bounds__(256) void scan_pass1(const __bf16* __restrict__ Y,
                                                  float* __restrict__ Ac,
                                                  float* __restrict__ Bc) {
  int tid = blockIdx.x * 256 + threadIdx.x;  // 0 .. NCH*BH/8-1
  int c = tid >> 11;                          // BH/8 = 2048 threads per chunk
  int r = tid & 2047;
  int bh0 = r << 3;                           // first of 8 consecutive bh
  int b = bh0 >> 10, h0 = bh0 & (Hd - 1);
  const size_t sstep = (size_t)Bsz * N;
  size_t base0 = (size_t)b * N + h0 + (size_t)(c * CS) * sstep;
  float A[8], Bv[8];
#pragma unroll
  for (int v = 0; v < 8; ++v) { A[v] = 1.0f; Bv[v] = 0.0f; }
#pragma unroll
  for (int j0 = 0; j0 < CS; j0 += 8) {
    bf16x8 zv[8], fv[8];
#pragma unroll
    for (int j = 0; j < 8; ++j) {
      size_t base = base0 + (size_t)(j0 + j) * sstep;
      zv[j] = *(const bf16x8*)(Y + base);
      fv[j] = *(const bf16x8*)(Y + base + Hd);
    }
#pragma unroll
    for (int j = 0; j < 8; ++j) {
#pragma unroll
      for (int v = 0; v < 8; ++v) {
        float z = (float)zv[j][v], f = (float)fv[j][v];
        float a = 1.0f - f;
        Bv[v] = fmaf(a, Bv[v], f * z);
        A[v] *= a;
      }
    }
  }
  int ob = c * BH + bh0;
  f32x4 a0, a1, b0, b1;
#pragma unroll
  for (int v = 0; v < 4; ++v) { a0[v] = A[v]; a1[v] = A[v + 4]; b0[v] = Bv[v]; b1[v] = Bv[v + 4]; }
  *(f32x4*)(Ac + ob) = a0;
  *(f32x4*)(Ac + ob + 4) = a1;
  *(f32x4*)(Bc + ob) = b0;
  *(f32x4*)(Bc + ob + 4) = b1;
}

// pass2: chain chunk states; emit per-chunk h_in and C_last (R3/R9-proven)
__global__ __launch_bounds__(256) void scan_pass2(const float* __restrict__ Ac,
                                                  const float* __restrict__ Bc,
                                                  float* __restrict__ hin,
                                                  float* __restrict__ clast) {
  int bh = blockIdx.x * 256 + threadIdx.x;  // 0..BH-1
  float h = 0.0f;
#pragma unroll 8
  for (int c = 0; c < NCH; ++c) {
    hin[c * BH + bh] = h;
    h = fmaf(Ac[c * BH + bh], h, Bc[c * BH + bh]);
  }
  clast[bh] = h;
}

// pass3: replay chunk from known h_in, write Hout = o * h (R3/R9-proven)
__global__ __launch_bounds__(256) void scan_pass3(const __bf16* __restrict__ Y,
                                                  const float* __restrict__ hin,
                                                  float* __restrict__ hout) {
  int tid = blockIdx.x * 256 + threadIdx.x;
  int c = tid >> 11;
  int r = tid & 2047;
  int bh0 = r << 3;
  int b = bh0 >> 10, h0 = bh0 & (Hd - 1);
  const size_t sstep = (size_t)Bsz * N;
  size_t base0 = (size_t)b * N + h0 + (size_t)(c * CS) * sstep;
  size_t obase0 = (size_t)b * Hd + h0 + (size_t)(c * CS) * BH;
  float hp[8];
  {
    f32x4 h04 = *(const f32x4*)(hin + c * BH + bh0);
    f32x4 h14 = *(const f32x4*)(hin + c * BH + bh0 + 4);
#pragma unroll
    for (int v = 0; v < 4; ++v) { hp[v] = h04[v]; hp[v + 4] = h14[v]; }
  }
#pragma unroll
  for (int j0 = 0; j0 < CS; j0 += 8) {
    bf16x8 zv[8], fv[8], ov[8];
#pragma unroll
    for (int j = 0; j < 8; ++j) {
      size_t base = base0 + (size_t)(j0 + j) * sstep;
      zv[j] = *(const bf16x8*)(Y + base);
      fv[j] = *(const bf16x8*)(Y + base + Hd);
      ov[j] = *(const bf16x8*)(Y + base + 2 * Hd);
    }
#pragma unroll
    for (int j = 0; j < 8; ++j) {
      f32x4 o0, o1;
#pragma unroll
      for (int v = 0; v < 8; ++v) {
        float z = (float)zv[j][v], f = (float)fv[j][v], o = (float)ov[j][v];
        hp[v] = fmaf(f, z - hp[v], hp[v]);  // f*z + (1-f)*h
        float out = o * hp[v];
        if (v < 4) o0[v] = out; else o1[v - 4] = out;
      }
      size_t ob = obase0 + (size_t)(j0 + j) * BH;
      *(f32x4*)(hout + ob) = o0;
      *(f32x4*)(hout + ob + 4) = o1;
    }
  }
}

extern "C" void kernel_launch(void* const* d_in, const int* in_sizes, int n_in,
                              void* d_out, int out_size, void* d_ws, size_t ws_size,
                              hipStream_t stream) {
  const float* X = (const float*)d_in[0];    // [1024,16,1024]
  const float* W = (const float*)d_in[1];    // [3072,1024]
  const float* bias = (const float*)d_in[2]; // [3072]
  float* out = (float*)d_out;                // Hout (16777216) + C_last (16384)

  char* ws = (char*)d_ws;
  __bf16* Xb = (__bf16*)ws;                      // 33,554,432 B
  __bf16* Wb = (__bf16*)(ws + 33554432);         // 6,291,456 B
  __bf16* Yv = (__bf16*)(ws + 39845888);         // 100,663,296 B (bf16 Y)
  float* Ac = (float*)(ws + 39845888 + 100663296);
  float* Bc = Ac + NCH * BH;                     // 4 MB each (NCH=64)
  float* hin = Bc + NCH * BH;

  convert_all<<<9728, 256, 0, stream>>>(X, W, Xb, Wb);

  dim3 ggrid((M / BM) * (N / BN));   // 3072
  dim3 vgrid(NCH * BH / 8 / 256);    // 512 blocks
  gemm_act<<<ggrid, 256, 0, stream>>>(Xb, Wb, bias, Yv);
  scan_pass1<<<vgrid, 256, 0, stream>>>(Yv, Ac, Bc);
  scan_pass2<<<BH / 256, 256, 0, stream>>>(Ac, Bc, hin, out + 16777216);
  scan_pass3<<<vgrid, 256, 0, stream>>>(Yv, hin, out);
}

// Round 11
// 301.011 us; speedup vs baseline: 1.0451x; 1.0451x over previous
//
#include <hip/hip_runtime.h>
#include <hip/hip_bf16.h>
#include <stdint.h>

typedef __bf16 bf16x8 __attribute__((ext_vector_type(8)));
typedef float f32x4 __attribute__((ext_vector_type(4)));

constexpr int S = 1024, Bsz = 16, Hd = 1024;
constexpr int M = S * Bsz;   // 16384
constexpr int N = 3 * Hd;    // 3072
constexpr int K = 1024;
constexpr int BM = 128, BN = 128, BK = 64;   // BK=64 + granule-XOR swizzle (T2, rule #21)
constexpr int NCH = 64, CS = S / NCH;  // 64 chunks x 16 steps
constexpr int BH = Bsz * Hd;           // 16384
constexpr int EP = 136;                // epilogue LDS row stride (272B, 16B-aligned)

__device__ __forceinline__ float fast_sigmoid(float x) { return 1.0f / (1.0f + __expf(-x)); }
__device__ __forceinline__ float fast_tanh(float x) { return 2.0f / (1.0f + __expf(-2.0f * x)) - 1.0f; }

// async global->LDS 16B per lane; LDS dest is wave-uniform base + lane*16
__device__ __forceinline__ void gld_lds16(const __bf16* g, __bf16* l) {
  __builtin_amdgcn_global_load_lds(
      (const __attribute__((address_space(1))) void*)g,
      (__attribute__((address_space(3))) void*)l,
      16, 0, 0);
}

// ---- fp32 -> bf16 conversion for BOTH X and W in one launch ----
__global__ void convert_all(const float* __restrict__ X, const float* __restrict__ W,
                            __bf16* __restrict__ Xb, __bf16* __restrict__ Wb) {
  int i = blockIdx.x * blockDim.x + threadIdx.x;  // 0 .. 2490367
  const float* src; __bf16* dst; int idx;
  if (i < 2097152) { src = X; dst = Xb; idx = i; }
  else             { src = W; dst = Wb; idx = i - 2097152; }
  const float4* s4 = (const float4*)src;
  float4 a = s4[2 * idx], b = s4[2 * idx + 1];
  bf16x8 v;
  v[0] = (__bf16)a.x; v[1] = (__bf16)a.y; v[2] = (__bf16)a.z; v[3] = (__bf16)a.w;
  v[4] = (__bf16)b.x; v[5] = (__bf16)b.y; v[6] = (__bf16)b.z; v[7] = (__bf16)b.w;
  *((bf16x8*)dst + idx) = v;
}

// ---- bf16 MFMA GEMM (NT: C[m,n] = sum_k A[m,k]*W[n,k]) + bias + activation ----
// R9 2-barrier loop + BK=64 (half the barrier drains per MFMA) + T2 granule
// swizzle: LDS[row][g] holds G[row][g ^ (row&7)] — achieved by pre-swizzling
// the GLOBAL source granule (linear gld_lds dest, rule #21) and XORing the
// ds_read granule. Spreads a wave-b128 read over 8 bank-groups (was 4).
// R3/R9-proven full-tile LDS epilogue unchanged.
__global__ __launch_bounds__(256) void gemm_act(const __bf16* __restrict__ A,
                                                const __bf16* __restrict__ Bw,
                                                const float* __restrict__ bias,
                                                __bf16* __restrict__ Y) {
  // staging: As/Bs 128x64 each (16KB ea = 32KB); epilogue union [128][EP] = 34816B
  __shared__ __align__(16) __bf16 smem[BM * EP];  // 34816 B
  __bf16* As = smem;            // 8192 elems
  __bf16* Bs = smem + 8192;     // 8192 elems
  const int t = threadIdx.x;
  const int lane = t & 63;
  const int wave = t >> 6;
  const int wm = wave >> 1, wn = wave & 1;
  const int tn = blockIdx.x % (N / BN);   // natural order (XCD swizzle hurt FETCH, R3)
  const int tm = blockIdx.x / (N / BN);
  const int m0 = tm * BM, n0 = tn * BN;
  const int lrow = lane & 15;
  const int quad = lane >> 4;
  const int l7 = lrow & 7;

  // staging: 4 issues/operand; issue i covers rows i*32 + (t>>3), granule (t&7)
  // SOURCE granule pre-swizzled: sg = (t&7) ^ (srow&7)  (rows step by 32 ≡ 0 mod 8)
  const int srow = t >> 3;                  // 0..31
  const int sg = (t & 7) ^ (srow & 7);      // inverse-swizzled source granule
  const __bf16* gA = A + (size_t)(m0 + srow) * K + sg * 8;
  const __bf16* gB = Bw + (size_t)(n0 + srow) * K + sg * 8;
  // wave-uniform LDS dest (elems): issue i at i*2048, wave at +wave*512
  __bf16* lA = As + wave * 512;
  __bf16* lB = Bs + wave * 512;

  f32x4 acc[4][4] = {};

  for (int k0 = 0; k0 < K; k0 += BK) {
    __syncthreads();
#pragma unroll
    for (int i = 0; i < 4; ++i) {
      gld_lds16(gA + (size_t)i * 32 * K, lA + i * 2048);
      gld_lds16(gB + (size_t)i * 32 * K, lB + i * 2048);
    }
    gA += BK; gB += BK;
    __syncthreads();   // implicit vmcnt(0): tile resident

#pragma unroll
    for (int kk = 0; kk < 2; ++kk) {
      // swizzled read granule: g' = (kk*4+quad) ^ (lrow&7); row*64 + g'*8 elems
      const int gsw = ((kk * 4 + quad) ^ l7) * 8;
      bf16x8 af[4], bfr[4];
#pragma unroll
      for (int mi = 0; mi < 4; ++mi)
        af[mi] = *(const bf16x8*)(&As[(wm * 64 + mi * 16 + lrow) * BK + gsw]);
#pragma unroll
      for (int ni = 0; ni < 4; ++ni)
        bfr[ni] = *(const bf16x8*)(&Bs[(wn * 64 + ni * 16 + lrow) * BK + gsw]);
#pragma unroll
      for (int mi = 0; mi < 4; ++mi)
#pragma unroll
        for (int ni = 0; ni < 4; ++ni)
          acc[mi][ni] = __builtin_amdgcn_mfma_f32_16x16x32_bf16(af[mi], bfr[ni], acc[mi][ni], 0, 0, 0);
    }
  }

  // ---- epilogue (R3/R9-proven): activation -> LDS [128][EP] -> coalesced global ----
  __syncthreads();  // all ds_reads done; reuse smem as epilogue tile
#pragma unroll
  for (int ni = 0; ni < 4; ++ni) {
    int colL = wn * 64 + ni * 16 + lrow;
    int col = n0 + colL;
    float bv = bias[col];
    bool is_tanh = (col < Hd);
#pragma unroll
    for (int mi = 0; mi < 4; ++mi) {
#pragma unroll
      for (int r = 0; r < 4; ++r) {
        int rowL = wm * 64 + mi * 16 + quad * 4 + r;  // C/D: col=lane&15, row=quad*4+r
        float y = acc[mi][ni][r] + bv;
        float v = is_tanh ? fast_tanh(y) : fast_sigmoid(y);
        smem[rowL * EP + colL] = (__bf16)v;
      }
    }
  }
  __syncthreads();
  // 128 rows x 128 cols bf16: each thread stores one bf16x8; 16 threads cover a 256B row
#pragma unroll
  for (int it = 0; it < 8; ++it) {
    int slot = it * 256 + t;
    int rowL = slot >> 4;
    int cw = slot & 15;
    bf16x8 vv = *(const bf16x8*)(&smem[rowL * EP + cw * 8]);
    *(bf16x8*)(&Y[(size_t)(m0 + rowL) * N + n0 + cw * 8]) = vv;
  }
}

// ---- chunked affine scan: h_t = f*z + (1-f)*h == a*h + b, a=1-f, b=f*z ----
// pass1: per-chunk composition (A,B): h_out = A*h_in + B  (R3/R9-proven)
__global__ __launch_bounds__(256) void scan_pass1(const __bf16* __restrict__ Y,
                                                  float* __restrict__ Ac,
                                                  float* __restrict__ Bc) {
  int tid = blockIdx.x * 256 + threadIdx.x;  // 0 .. NCH*BH/8-1
  int c = tid >> 11;                          // BH/8 = 2048 threads per chunk
  int r = tid & 2047;
  int bh0 = r << 3;                           // first of 8 consecutive bh
  int b = bh0 >> 10, h0 = bh0 & (Hd - 1);
  const size_t sstep = (size_t)Bsz * N;
  size_t base0 = (size_t)b * N + h0 + (size_t)(c * CS) * sstep;
  float A[8], Bv[8];
#pragma unroll
  for (int v = 0; v < 8; ++v) { A[v] = 1.0f; Bv[v] = 0.0f; }
#pragma unroll
  for (int j0 = 0; j0 < CS; j0 += 8) {
    bf16x8 zv[8], fv[8];
#pragma unroll
    for (int j = 0; j < 8; ++j) {
      size_t base = base0 + (size_t)(j0 + j) * sstep;
      zv[j] = *(const bf16x8*)(Y + base);
      fv[j] = *(const bf16x8*)(Y + base + Hd);
    }
#pragma unroll
    for (int j = 0; j < 8; ++j) {
#pragma unroll
      for (int v = 0; v < 8; ++v) {
        float z = (float)zv[j][v], f = (float)fv[j][v];
        float a = 1.0f - f;
        Bv[v] = fmaf(a, Bv[v], f * z);
        A[v] *= a;
      }
    }
  }
  int ob = c * BH + bh0;
  f32x4 a0, a1, b0, b1;
#pragma unroll
  for (int v = 0; v < 4; ++v) { a0[v] = A[v]; a1[v] = A[v + 4]; b0[v] = Bv[v]; b1[v] = Bv[v + 4]; }
  *(f32x4*)(Ac + ob) = a0;
  *(f32x4*)(Ac + ob + 4) = a1;
  *(f32x4*)(Bc + ob) = b0;
  *(f32x4*)(Bc + ob + 4) = b1;
}

// pass2: chain chunk states; emit per-chunk h_in and C_last (R3/R9-proven)
__global__ __launch_bounds__(256) void scan_pass2(const float* __restrict__ Ac,
                                                  const float* __restrict__ Bc,
                                                  float* __restrict__ hin,
                                                  float* __restrict__ clast) {
  int bh = blockIdx.x * 256 + threadIdx.x;  // 0..BH-1
  float h = 0.0f;
#pragma unroll 8
  for (int c = 0; c < NCH; ++c) {
    hin[c * BH + bh] = h;
    h = fmaf(Ac[c * BH + bh], h, Bc[c * BH + bh]);
  }
  clast[bh] = h;
}

// pass3: replay chunk from known h_in, write Hout = o * h (R3/R9-proven)
__global__ __launch_bounds__(256) void scan_pass3(const __bf16* __restrict__ Y,
                                                  const float* __restrict__ hin,
                                                  float* __restrict__ hout) {
  int tid = blockIdx.x * 256 + threadIdx.x;
  int c = tid >> 11;
  int r = tid & 2047;
  int bh0 = r << 3;
  int b = bh0 >> 10, h0 = bh0 & (Hd - 1);
  const size_t sstep = (size_t)Bsz * N;
  size_t base0 = (size_t)b * N + h0 + (size_t)(c * CS) * sstep;
  size_t obase0 = (size_t)b * Hd + h0 + (size_t)(c * CS) * BH;
  float hp[8];
  {
    f32x4 h04 = *(const f32x4*)(hin + c * BH + bh0);
    f32x4 h14 = *(const f32x4*)(hin + c * BH + bh0 + 4);
#pragma unroll
    for (int v = 0; v < 4; ++v) { hp[v] = h04[v]; hp[v + 4] = h14[v]; }
  }
#pragma unroll
  for (int j0 = 0; j0 < CS; j0 += 8) {
    bf16x8 zv[8], fv[8], ov[8];
#pragma unroll
    for (int j = 0; j < 8; ++j) {
      size_t base = base0 + (size_t)(j0 + j) * sstep;
      zv[j] = *(const bf16x8*)(Y + base);
      fv[j] = *(const bf16x8*)(Y + base + Hd);
      ov[j] = *(const bf16x8*)(Y + base + 2 * Hd);
    }
#pragma unroll
    for (int j = 0; j < 8; ++j) {
      f32x4 o0, o1;
#pragma unroll
      for (int v = 0; v < 8; ++v) {
        float z = (float)zv[j][v], f = (float)fv[j][v], o = (float)ov[j][v];
        hp[v] = fmaf(f, z - hp[v], hp[v]);  // f*z + (1-f)*h
        float out = o * hp[v];
        if (v < 4) o0[v] = out; else o1[v - 4] = out;
      }
      size_t ob = obase0 + (size_t)(j0 + j) * BH;
      *(f32x4*)(hout + ob) = o0;
      *(f32x4*)(hout + ob + 4) = o1;
    }
  }
}

extern "C" void kernel_launch(void* const* d_in, const int* in_sizes, int n_in,
                              void* d_out, int out_size, void* d_ws, size_t ws_size,
                              hipStream_t stream) {
  const float* X = (const float*)d_in[0];    // [1024,16,1024]
  const float* W = (const float*)d_in[1];    // [3072,1024]
  const float* bias = (const float*)d_in[2]; // [3072]
  float* out = (float*)d_out;                // Hout (16777216) + C_last (16384)

  char* ws = (char*)d_ws;
  __bf16* Xb = (__bf16*)ws;                      // 33,554,432 B
  __bf16* Wb = (__bf16*)(ws + 33554432);         // 6,291,456 B
  __bf16* Yv = (__bf16*)(ws + 39845888);         // 100,663,296 B (bf16 Y)
  float* Ac = (float*)(ws + 39845888 + 100663296);
  float* Bc = Ac + NCH * BH;                     // 4 MB each (NCH=64)
  float* hin = Bc + NCH * BH;

  convert_all<<<9728, 256, 0, stream>>>(X, W, Xb, Wb);

  dim3 ggrid((M / BM) * (N / BN));   // 3072
  dim3 vgrid(NCH * BH / 8 / 256);    // 512 blocks
  gemm_act<<<ggrid, 256, 0, stream>>>(Xb, Wb, bias, Yv);
  scan_pass1<<<vgrid, 256, 0, stream>>>(Yv, Ac, Bc);
  scan_pass2<<<BH / 256, 256, 0, stream>>>(Ac, Bc, hin, out + 16777216);
  scan_pass3<<<vgrid, 256, 0, stream>>>(Yv, hin, out);
}